// Round 3
// baseline (530.937 us; speedup 1.0000x reference)
//
#include <hip/hip_runtime.h>
#include <hip/hip_bf16.h>

// ---------- types ----------
using short8  = __attribute__((ext_vector_type(8))) short;
using ushort8 = __attribute__((ext_vector_type(8))) unsigned short;
using f32x4   = __attribute__((ext_vector_type(4))) float;

#define GLB(p)  ((const __attribute__((address_space(1))) void*)(p))
#define LDSP(p) ((__attribute__((address_space(3))) void*)(p))

static __device__ __forceinline__ unsigned short f2bf(float f) {
    union { float f; unsigned u; } v; v.f = f;
    unsigned u = v.u;
    u += 0x7fffu + ((u >> 16) & 1u);   // round-to-nearest-even
    return (unsigned short)(u >> 16);
}
static __device__ __forceinline__ unsigned short f2bfc(float f) {
    return __builtin_bit_cast(unsigned short, __float2bfloat16(f));
}

// ---------- problem constants ----------
#define K_DIM 2048
#define N_DIM 2048
#define M_TOTAL 26112
#define N_GROUPS 8

// ---------- kernel: B [K][N] fp32 -> Bt [N][K] bf16 (transpose + convert) ----------
__global__ __launch_bounds__(256) void cvt_bt_kernel(const float* __restrict__ B,
                                                     unsigned short* __restrict__ Bt) {
    __shared__ float t[32][33];
    int bx = blockIdx.x, by = blockIdx.y;
    int tx = threadIdx.x, ty = threadIdx.y;
#pragma unroll
    for (int i = 0; i < 32; i += 8)
        t[ty + i][tx] = B[(long)(by * 32 + ty + i) * N_DIM + bx * 32 + tx];
    __syncthreads();
#pragma unroll
    for (int i = 0; i < 32; i += 8)
        Bt[(long)(bx * 32 + ty + i) * K_DIM + by * 32 + tx] = f2bf(t[tx][ty + i]);
}

// ---------- main GEMM: 256x256 8-phase, fused fp32->bf16 A staging ----------
// C[M][N] fp32 = A(fp32, 8 ragged groups)[M][K] * Bt[N][K]^T (bf16).
// B: global_load_lds (linear dest, pre-swizzled source). A: reg-staged fp32 loads
// (issued ph1) -> vmcnt(4) + cvt + swizzled ds_write_b128 x4 (ph3), T14-style.

#define PBAR() __builtin_amdgcn_s_barrier()
#define LGKM0() asm volatile("s_waitcnt lgkmcnt(0)" ::: "memory")
#define VMC(n)  asm volatile("s_waitcnt vmcnt(" #n ")" ::: "memory")

#define ST_B(BUF, H, L, TT)                                                        \
    __builtin_amdgcn_global_load_lds(                                              \
        GLB(bSt + (long)((H) * 128 + (L) * 64) * K_DIM + (TT) * 64),               \
        LDSP(lds + (BUF) * 32768 + 16384 + (H) * 8192 + (L) * 4096 + w * 512), 16, 0, 0)

// 8 independent MFMAs (one quadrant, one k-step); same-acc reuse distance = 8
#define MMQ(MH, NH, AV, BV)                                                        \
    _Pragma("unroll") for (int i = 0; i < 4; ++i)                                  \
    _Pragma("unroll") for (int j = 0; j < 2; ++j)                                  \
        acc[(MH) * 4 + i][(NH) * 2 + j] = __builtin_amdgcn_mfma_f32_16x16x32_bf16( \
            AV[i], BV[j], acc[(MH) * 4 + i][(NH) * 2 + j], 0, 0, 0);

// issue the 8 fp32 A loads for k-tile T1 (thread = one row, 32 consecutive k)
#define ALOAD(T1)                                                                  \
    do { const float* _ap = aLd + (T1) * 64;                                       \
        ax0 = *(const float4*)(_ap);      ax1 = *(const float4*)(_ap + 4);         \
        ax2 = *(const float4*)(_ap + 8);  ax3 = *(const float4*)(_ap + 12);        \
        ax4 = *(const float4*)(_ap + 16); ax5 = *(const float4*)(_ap + 20);        \
        ax6 = *(const float4*)(_ap + 24); ax7 = *(const float4*)(_ap + 28); } while (0)

// convert 32 f32 -> 32 bf16 and write 4 swizzled b128 chunks into buffer BWR's A region
#define AWRITE(BWR)                                                                \
    do { unsigned short* wb = lds + (BWR) * 32768 + awOfs;                         \
        ushort8 o0, o1, o2, o3;                                                    \
        o0[0]=f2bfc(ax0.x); o0[1]=f2bfc(ax0.y); o0[2]=f2bfc(ax0.z); o0[3]=f2bfc(ax0.w); \
        o0[4]=f2bfc(ax1.x); o0[5]=f2bfc(ax1.y); o0[6]=f2bfc(ax1.z); o0[7]=f2bfc(ax1.w); \
        o1[0]=f2bfc(ax2.x); o1[1]=f2bfc(ax2.y); o1[2]=f2bfc(ax2.z); o1[3]=f2bfc(ax2.w); \
        o1[4]=f2bfc(ax3.x); o1[5]=f2bfc(ax3.y); o1[6]=f2bfc(ax3.z); o1[7]=f2bfc(ax3.w); \
        o2[0]=f2bfc(ax4.x); o2[1]=f2bfc(ax4.y); o2[2]=f2bfc(ax4.z); o2[3]=f2bfc(ax4.w); \
        o2[4]=f2bfc(ax5.x); o2[5]=f2bfc(ax5.y); o2[6]=f2bfc(ax5.z); o2[7]=f2bfc(ax5.w); \
        o3[0]=f2bfc(ax6.x); o3[1]=f2bfc(ax6.y); o3[2]=f2bfc(ax6.z); o3[3]=f2bfc(ax6.w); \
        o3[4]=f2bfc(ax7.x); o3[5]=f2bfc(ax7.y); o3[6]=f2bfc(ax7.z); o3[7]=f2bfc(ax7.w); \
        *(ushort8*)(wb + wq0) = o0; *(ushort8*)(wb + wq1) = o1;                    \
        *(ushort8*)(wb + wq2) = o2; *(ushort8*)(wb + wq3) = o3; } while (0)

// one K-tile (BK=64), 4 phases. DOA: reg-stage A(T+1) -> buf^1. DOB: gload B(T+2) -> buf.
#define TILE(BUF, T, DOA, DOB)                                                          \
    do {                                                                                \
        const unsigned short* pA = lds + (BUF) * 32768 + wm * 1024 + r16 * 64;          \
        const unsigned short* pB = lds + (BUF) * 32768 + 16384 + wn * 1024 + r16 * 64;  \
        short8 a0[4], a1[4], b00[2], b01[2], b10[2], b11[2];                            \
        float4 ax0, ax1, ax2, ax3, ax4, ax5, ax6, ax7;                                  \
        /* ---- ph1: read A-h0 + B-h0; issue A fp32 loads; MFMA m0n0 ---- */            \
        _Pragma("unroll") for (int i = 0; i < 4; ++i) {                                 \
            a0[i] = *(const short8*)(pA + i * 2048 + c0 * 8);                           \
            a1[i] = *(const short8*)(pA + i * 2048 + c1 * 8);                           \
        }                                                                               \
        _Pragma("unroll") for (int j = 0; j < 2; ++j) {                                 \
            b00[j] = *(const short8*)(pB + j * 4096 + c0 * 8);                          \
            b01[j] = *(const short8*)(pB + j * 4096 + c1 * 8);                          \
        }                                                                               \
        if (DOA) ALOAD((T) + 1);                                                        \
        PBAR(); LGKM0();                                                                \
        __builtin_amdgcn_s_setprio(1); MMQ(0, 0, a0, b00); MMQ(0, 0, a1, b01);          \
        __builtin_amdgcn_s_setprio(0); PBAR();                                          \
        /* ---- ph2: read B-h1; stage B(T+2)-h0; MFMA m0n1 ---- */                      \
        _Pragma("unroll") for (int j = 0; j < 2; ++j) {                                 \
            b10[j] = *(const short8*)(pB + 8192 + j * 4096 + c0 * 8);                   \
            b11[j] = *(const short8*)(pB + 8192 + j * 4096 + c1 * 8);                   \
        }                                                                               \
        if (DOB) { ST_B((BUF), 0, 0, (T) + 2); ST_B((BUF), 0, 1, (T) + 2); }            \
        PBAR(); LGKM0();                                                                \
        __builtin_amdgcn_s_setprio(1); MMQ(0, 1, a0, b10); MMQ(0, 1, a1, b11);          \
        __builtin_amdgcn_s_setprio(0); PBAR();                                          \
        /* ---- ph3: read A-h1; stage B(T+2)-h1; cvt+write A(T+1); MFMA m1n0 ---- */    \
        _Pragma("unroll") for (int i = 0; i < 4; ++i) {                                 \
            a0[i] = *(const short8*)(pA + 8192 + i * 2048 + c0 * 8);                    \
            a1[i] = *(const short8*)(pA + 8192 + i * 2048 + c1 * 8);                    \
        }                                                                               \
        if (DOB) { ST_B((BUF), 1, 0, (T) + 2); ST_B((BUF), 1, 1, (T) + 2); }            \
        if (DOA) {                                                                      \
            if (DOB) { VMC(4); } else { VMC(0); }                                       \
            AWRITE((BUF) ^ 1);                                                          \
        }                                                                               \
        PBAR(); LGKM0();                                                                \
        __builtin_amdgcn_s_setprio(1); MMQ(1, 0, a0, b00); MMQ(1, 0, a1, b01);          \
        __builtin_amdgcn_s_setprio(0); PBAR();                                          \
        /* ---- ph4: register-only; MFMA m1n1 ---- */                                   \
        __builtin_amdgcn_s_setprio(1); MMQ(1, 1, a0, b10); MMQ(1, 1, a1, b11);          \
        __builtin_amdgcn_s_setprio(0);                                                  \
    } while (0)

__global__ __launch_bounds__(512, 2) void gemm8_kernel(
        const float* __restrict__ A0, const float* __restrict__ A1,
        const float* __restrict__ A2, const float* __restrict__ A3,
        const float* __restrict__ A4, const float* __restrict__ A5,
        const float* __restrict__ A6, const float* __restrict__ A7,
        const unsigned short* __restrict__ Bt, float* __restrict__ C) {
    __shared__ unsigned short lds[65536];   // 128 KiB: 2 buf x (A 256x64 + B 256x64) bf16

    // grid = 102 mtiles * 8 ntiles = 816 (816 % 8 == 0 -> bijective XCD swizzle)
    int wg  = blockIdx.x;
    int swz = (wg & 7) * 102 + (wg >> 3);
    int mt  = swz >> 3, nt = swz & 7;
    int m0  = mt * 256, n0 = nt * 256;

    // group resolution (offsets/256: 0,16,24,28,60,62,74,98; all tiles group-pure)
    const float* aBase; int goff;
    if      (mt < 16) { aBase = A0; goff = 0;     }
    else if (mt < 24) { aBase = A1; goff = 4096;  }
    else if (mt < 28) { aBase = A2; goff = 6144;  }
    else if (mt < 60) { aBase = A3; goff = 7168;  }
    else if (mt < 62) { aBase = A4; goff = 15360; }
    else if (mt < 74) { aBase = A5; goff = 15872; }
    else if (mt < 98) { aBase = A6; goff = 18944; }
    else              { aBase = A7; goff = 25088; }

    int tid = threadIdx.x;
    int l   = tid & 63;
    int w   = tid >> 6;          // wave 0..7
    int wm  = w >> 2;            // 0..1
    int wn  = w & 3;             // 0..3
    int r16 = l & 15, kc = l >> 4, x = l & 7;
    int c0  = kc ^ x;            // swizzled chunk, k-step 0
    int c1  = (4 + kc) ^ x;      // swizzled chunk, k-step 1

    // B staging: per-thread pre-swizzled global source (linear gload_lds dest)
    int srow = tid >> 3;
    int sq   = (tid & 7) ^ (srow & 7);
    const unsigned short* bSt = Bt + (long)(n0 + srow) * K_DIM + sq * 8;

    // A staging: thread = row (tid>>1), k-half (tid&1)*32; swizzled ds_write offsets
    const float* aLd = aBase + (long)(m0 - goff + (tid >> 1)) * K_DIM + (tid & 1) * 32;
    int awOfs = (tid >> 1) * 64;
    int wq0 = ((((tid & 1) * 4 + 0) ^ ((tid >> 1) & 7)) * 8);
    int wq1 = ((((tid & 1) * 4 + 1) ^ ((tid >> 1) & 7)) * 8);
    int wq2 = ((((tid & 1) * 4 + 2) ^ ((tid >> 1) & 7)) * 8);
    int wq3 = ((((tid & 1) * 4 + 3) ^ ((tid >> 1) & 7)) * 8);

    f32x4 acc[8][4] = {};

    // ---- prologue: A(t0) regs -> buf0; B(t0) -> buf0, B(t1) -> buf1 ----
    {
        float4 ax0, ax1, ax2, ax3, ax4, ax5, ax6, ax7;
        ALOAD(0);
        ST_B(0, 0, 0, 0); ST_B(0, 0, 1, 0); ST_B(0, 1, 0, 0); ST_B(0, 1, 1, 0);
        ST_B(1, 0, 0, 1); ST_B(1, 0, 1, 1); ST_B(1, 1, 0, 1); ST_B(1, 1, 1, 1);
        VMC(8);            // A(t0) done (8 B-gloads outstanding)
        AWRITE(0);
        VMC(4);            // B(t0) done (B(t1) in flight)
        LGKM0(); PBAR();
    }

    // ---- main loop: 32 K-tiles ----
#pragma unroll 1
    for (int t = 0; t < 30; t += 2) {
        TILE(0, t, 1, 1);     PBAR();
        TILE(1, t + 1, 1, 1); PBAR();
    }
    TILE(0, 30, 1, 0); PBAR();   // loads A(31); vmcnt(0) drains everything
    TILE(1, 31, 0, 0);

    // ---- epilogue: C/D layout col=lane&15, row=(lane>>4)*4+q ----
    int orow = m0 + wm * 16 + (l >> 4) * 4;
    int ocol = n0 + wn * 16 + (l & 15);
#pragma unroll
    for (int i = 0; i < 8; ++i)
#pragma unroll
        for (int j = 0; j < 4; ++j)
#pragma unroll
            for (int q = 0; q < 4; ++q)
                C[(long)(orow + i * 32 + q) * N_DIM + (ocol + j * 64)] = acc[i][j][q];
}

// ---------- fallback: correct (slow) fp32 tiled GEMM, used only if ws too small ----------
__global__ void naive_gemm_kernel(const float* __restrict__ A, const float* __restrict__ B,
                                  float* __restrict__ C, int M) {
    __shared__ float As[16][16];
    __shared__ float Bs[16][17];
    int tx = threadIdx.x, ty = threadIdx.y;
    int row = blockIdx.y * 16 + ty;
    int col = blockIdx.x * 16 + tx;
    float s = 0.f;
    for (int k0 = 0; k0 < K_DIM; k0 += 16) {
        As[ty][tx] = A[(long)row * K_DIM + k0 + tx];
        Bs[ty][tx] = B[(long)(k0 + ty) * N_DIM + col];
        __syncthreads();
#pragma unroll
        for (int t = 0; t < 16; ++t) s += As[ty][t] * Bs[t][tx];
        __syncthreads();
    }
    C[(long)row * N_DIM + col] = s;
}

// ---------- host launcher ----------
extern "C" void kernel_launch(void* const* d_in, const int* in_sizes, int n_in,
                              void* d_out, int out_size, void* d_ws, size_t ws_size,
                              hipStream_t stream) {
    static const int g_m[N_GROUPS]   = {4096, 2048, 1024, 8192, 512, 3072, 6144, 1024};
    static const int g_off[N_GROUPS] = {0, 4096, 6144, 7168, 15360, 15872, 18944, 25088};

    float* C = (float*)d_out;
    const size_t need = (size_t)N_DIM * K_DIM * 2;   // Bt only

    if (ws_size >= need) {
        unsigned short* Bt = (unsigned short*)d_ws;
        cvt_bt_kernel<<<dim3(N_DIM / 32, K_DIM / 32), dim3(32, 8), 0, stream>>>(
            (const float*)d_in[8], Bt);
        gemm8_kernel<<<(M_TOTAL / 256) * (N_DIM / 256), 512, 0, stream>>>(
            (const float*)d_in[0], (const float*)d_in[1], (const float*)d_in[2],
            (const float*)d_in[3], (const float*)d_in[4], (const float*)d_in[5],
            (const float*)d_in[6], (const float*)d_in[7], Bt, C);
    } else {
        for (int g = 0; g < N_GROUPS; ++g)
            naive_gemm_kernel<<<dim3(N_DIM / 16, g_m[g] / 16), dim3(16, 16), 0, stream>>>(
                (const float*)d_in[g], (const float*)d_in[8], C + (size_t)g_off[g] * N_DIM,
                g_m[g]);
    }
}

// Round 4
// 296.426 us; speedup vs baseline: 1.7911x; 1.7911x over previous
//
#include <hip/hip_runtime.h>
#include <hip/hip_bf16.h>

// ---------- types ----------
using short8  = __attribute__((ext_vector_type(8))) short;
using ushort8 = __attribute__((ext_vector_type(8))) unsigned short;
using f32x4   = __attribute__((ext_vector_type(4))) float;

#define GLB(p)  ((const __attribute__((address_space(1))) void*)(p))
#define LDSP(p) ((__attribute__((address_space(3))) void*)(p))

static __device__ __forceinline__ unsigned short f2bf(float f) {
    union { float f; unsigned u; } v; v.f = f;
    unsigned u = v.u;
    u += 0x7fffu + ((u >> 16) & 1u);   // round-to-nearest-even
    return (unsigned short)(u >> 16);
}

// ---------- problem constants ----------
#define K_DIM 2048
#define N_DIM 2048
#define M_TOTAL 26112
#define N_GROUPS 8

// ---------- kernel 1: all A groups fp32 -> contiguous bf16 Acat (single launch) ----------
// 1632 blocks x 16 rows; every 16-row block lies in exactly one group.
__global__ __launch_bounds__(256) void cvt_a_all(
        const float* __restrict__ A0, const float* __restrict__ A1,
        const float* __restrict__ A2, const float* __restrict__ A3,
        const float* __restrict__ A4, const float* __restrict__ A5,
        const float* __restrict__ A6, const float* __restrict__ A7,
        unsigned short* __restrict__ Acat) {
    int b = blockIdx.x;
    const float* src; int gb;   // group base block
    if      (b < 256)  { src = A0; gb = 0;    }
    else if (b < 384)  { src = A1; gb = 256;  }
    else if (b < 448)  { src = A2; gb = 384;  }
    else if (b < 960)  { src = A3; gb = 448;  }
    else if (b < 992)  { src = A4; gb = 960;  }
    else if (b < 1184) { src = A5; gb = 992;  }
    else if (b < 1568) { src = A6; gb = 1184; }
    else               { src = A7; gb = 1568; }
    const float* s   = src  + (long)(b - gb) * 16 * K_DIM;
    unsigned short* d = Acat + (long)b * 16 * K_DIM;
    int t = threadIdx.x;
#pragma unroll 4
    for (int i = 0; i < 16; ++i) {
        long off = (long)i * K_DIM + t * 8;
        float4 x = *(const float4*)(s + off);
        float4 y = *(const float4*)(s + off + 4);
        ushort8 o;
        o[0] = f2bf(x.x); o[1] = f2bf(x.y); o[2] = f2bf(x.z); o[3] = f2bf(x.w);
        o[4] = f2bf(y.x); o[5] = f2bf(y.y); o[6] = f2bf(y.z); o[7] = f2bf(y.w);
        *(ushort8*)(d + off) = o;
    }
}

// ---------- kernel 2: B [K][N] fp32 -> Bt [N][K] bf16 (transpose + convert) ----------
__global__ __launch_bounds__(256) void cvt_bt_kernel(const float* __restrict__ B,
                                                     unsigned short* __restrict__ Bt) {
    __shared__ float t[32][33];
    int bx = blockIdx.x, by = blockIdx.y;
    int tx = threadIdx.x, ty = threadIdx.y;
#pragma unroll
    for (int i = 0; i < 32; i += 8)
        t[ty + i][tx] = B[(long)(by * 32 + ty + i) * N_DIM + bx * 32 + tx];
    __syncthreads();
#pragma unroll
    for (int i = 0; i < 32; i += 8)
        Bt[(long)(bx * 32 + ty + i) * K_DIM + by * 32 + tx] = f2bf(t[tx][ty + i]);
}

// ---------- kernel 3: 256x256 8-phase bf16 GEMM (T1+T2+T3+T4+T5) ----------
// C[M_TOTAL][N] fp32 = Acat[M][K] bf16 * Bt[N][K]^T bf16.  BK=64, 8 waves (2Mx4N),
// 128 KiB LDS double buffer, raw s_barrier, counted vmcnt(6) at tile end only,
// XOR-swizzled LDS (pre-swizzled global src + swizzled ds_read; linear gload_lds dest).

#define PBAR() __builtin_amdgcn_s_barrier()
#define LGKM0() asm volatile("s_waitcnt lgkmcnt(0)" ::: "memory")
#define VMC(n)  asm volatile("s_waitcnt vmcnt(" #n ")" ::: "memory")

#define ST_A(BUF, H, L, TT)                                                        \
    __builtin_amdgcn_global_load_lds(                                              \
        GLB(aSt + (long)((H) * 128 + (L) * 64) * K_DIM + (TT) * 64),               \
        LDSP(lds + (BUF) * 32768 + (H) * 8192 + (L) * 4096 + w * 512), 16, 0, 0)
#define ST_B(BUF, H, L, TT)                                                        \
    __builtin_amdgcn_global_load_lds(                                              \
        GLB(bSt + (long)((H) * 128 + (L) * 64) * K_DIM + (TT) * 64),               \
        LDSP(lds + (BUF) * 32768 + 16384 + (H) * 8192 + (L) * 4096 + w * 512), 16, 0, 0)

// 8 independent MFMAs (one quadrant, one k-step); same-acc reuse distance = 8
#define MMQ(MH, NH, AV, BV)                                                        \
    _Pragma("unroll") for (int i = 0; i < 4; ++i)                                  \
    _Pragma("unroll") for (int j = 0; j < 2; ++j)                                  \
        acc[(MH) * 4 + i][(NH) * 2 + j] = __builtin_amdgcn_mfma_f32_16x16x32_bf16( \
            AV[i], BV[j], acc[(MH) * 4 + i][(NH) * 2 + j], 0, 0, 0);

// one K-tile (BK=64) = 4 phases. DO1: stage A(T+1)-h1 -> buf^1.
// DO2: stage A(T+2)-h0 (ph2), B(T+2)-h0 (ph3), B(T+2)-h1 (ph4) -> buf.
#define TILE(BUF, T, DO1, DO2)                                                          \
    do {                                                                                \
        const unsigned short* pA = lds + (BUF) * 32768 + wm * 1024 + r16 * 64;          \
        const unsigned short* pB = lds + (BUF) * 32768 + 16384 + wn * 1024 + r16 * 64;  \
        short8 a0[4], a1[4], b00[2], b01[2], b10[2], b11[2];                            \
        /* ---- ph1: read A-h0 (8) + B-h0 (4); MFMA m0n0 ---- */                        \
        _Pragma("unroll") for (int i = 0; i < 4; ++i) {                                 \
            a0[i] = *(const short8*)(pA + i * 2048 + c0 * 8);                           \
            a1[i] = *(const short8*)(pA + i * 2048 + c1 * 8);                           \
        }                                                                               \
        _Pragma("unroll") for (int j = 0; j < 2; ++j) {                                 \
            b00[j] = *(const short8*)(pB + j * 4096 + c0 * 8);                          \
            b01[j] = *(const short8*)(pB + j * 4096 + c1 * 8);                          \
        }                                                                               \
        if (DO1) { ST_A((BUF) ^ 1, 1, 0, (T) + 1); ST_A((BUF) ^ 1, 1, 1, (T) + 1); }    \
        PBAR(); LGKM0();                                                                \
        __builtin_amdgcn_s_setprio(1); MMQ(0, 0, a0, b00); MMQ(0, 0, a1, b01);          \
        __builtin_amdgcn_s_setprio(0); PBAR();                                          \
        /* ---- ph2: read B-h1 (4); stage A(T+2)-h0; MFMA m0n1 ---- */                  \
        _Pragma("unroll") for (int j = 0; j < 2; ++j) {                                 \
            b10[j] = *(const short8*)(pB + 8192 + j * 4096 + c0 * 8);                   \
            b11[j] = *(const short8*)(pB + 8192 + j * 4096 + c1 * 8);                   \
        }                                                                               \
        if (DO2) { ST_A((BUF), 0, 0, (T) + 2); ST_A((BUF), 0, 1, (T) + 2); }            \
        PBAR(); LGKM0();                                                                \
        __builtin_amdgcn_s_setprio(1); MMQ(0, 1, a0, b10); MMQ(0, 1, a1, b11);          \
        __builtin_amdgcn_s_setprio(0); PBAR();                                          \
        /* ---- ph3: read A-h1 (8); stage B(T+2)-h0; MFMA m1n0 ---- */                  \
        _Pragma("unroll") for (int i = 0; i < 4; ++i) {                                 \
            a0[i] = *(const short8*)(pA + 8192 + i * 2048 + c0 * 8);                    \
            a1[i] = *(const short8*)(pA + 8192 + i * 2048 + c1 * 8);                    \
        }                                                                               \
        if (DO2) { ST_B((BUF), 0, 0, (T) + 2); ST_B((BUF), 0, 1, (T) + 2); }            \
        PBAR(); LGKM0();                                                                \
        __builtin_amdgcn_s_setprio(1); MMQ(1, 0, a0, b00); MMQ(1, 0, a1, b01);          \
        __builtin_amdgcn_s_setprio(0); PBAR();                                          \
        /* ---- ph4: register-only MFMA m1n1 (no barrier; staged region's readers       \
                2 barriers past) ---- */                                                \
        if (DO2) { ST_B((BUF), 1, 0, (T) + 2); ST_B((BUF), 1, 1, (T) + 2); }            \
        __builtin_amdgcn_s_setprio(1); MMQ(1, 1, a0, b10); MMQ(1, 1, a1, b11);          \
        __builtin_amdgcn_s_setprio(0);                                                  \
    } while (0)

__global__ __launch_bounds__(512, 2) void gemm8_kernel(const unsigned short* __restrict__ Acat,
                                                       const unsigned short* __restrict__ Bt,
                                                       float* __restrict__ C) {
    __shared__ unsigned short lds[65536];   // 128 KiB: 2 buf x (A 256x64 + B 256x64) bf16

    // grid = 102 mtiles * 8 ntiles = 816 (816 % 8 == 0 -> bijective XCD swizzle)
    int wg  = blockIdx.x;
    int swz = (wg & 7) * 102 + (wg >> 3);
    int mt  = swz >> 3, nt = swz & 7;
    int m0  = mt * 256, n0 = nt * 256;

    int tid = threadIdx.x;
    int l   = tid & 63;
    int w   = tid >> 6;          // wave 0..7
    int wm  = w >> 2;            // 0..1
    int wn  = w & 3;             // 0..3
    int r16 = l & 15, kc = l >> 4, x = l & 7;
    int c0  = kc ^ x;            // swizzled chunk, k-step 0
    int c1  = (4 + kc) ^ x;      // swizzled chunk, k-step 1

    // per-thread pre-swizzled global stage sources (linear gload_lds dest)
    int srow = tid >> 3;
    int sq   = (tid & 7) ^ (srow & 7);
    const unsigned short* aSt = Acat + (long)(m0 + srow) * K_DIM + sq * 8;
    const unsigned short* bSt = Bt   + (long)(n0 + srow) * K_DIM + sq * 8;

    f32x4 acc[8][4] = {};

    // prologue: tile0 full (8) + tile1 A0,B0,B1 (6); wait tile0 (vmcnt 6)
    ST_A(0, 0, 0, 0); ST_A(0, 0, 1, 0); ST_A(0, 1, 0, 0); ST_A(0, 1, 1, 0);
    ST_B(0, 0, 0, 0); ST_B(0, 0, 1, 0); ST_B(0, 1, 0, 0); ST_B(0, 1, 1, 0);
    ST_A(1, 0, 0, 1); ST_A(1, 0, 1, 1);
    ST_B(1, 0, 0, 1); ST_B(1, 0, 1, 1); ST_B(1, 1, 0, 1); ST_B(1, 1, 1, 1);
    VMC(6); PBAR();

    // main loop: 32 K-tiles, 2 per iteration
#pragma unroll 1
    for (int t = 0; t < 30; t += 2) {
        TILE(0, t, 1, 1);     VMC(6); PBAR();
        TILE(1, t + 1, 1, 1); VMC(6); PBAR();
    }
    TILE(0, 30, 1, 0); VMC(0); PBAR();
    TILE(1, 31, 0, 0);

    // epilogue: C/D layout col=lane&15, row=(lane>>4)*4+q
    int orow = m0 + wm * 16 + (l >> 4) * 4;
    int ocol = n0 + wn * 16 + (l & 15);
#pragma unroll
    for (int i = 0; i < 8; ++i)
#pragma unroll
        for (int j = 0; j < 4; ++j)
#pragma unroll
            for (int q = 0; q < 4; ++q)
                C[(long)(orow + i * 32 + q) * N_DIM + (ocol + j * 64)] = acc[i][j][q];
}

// ---------- fallback: correct (slow) fp32 tiled GEMM, used only if ws too small ----------
__global__ void naive_gemm_kernel(const float* __restrict__ A, const float* __restrict__ B,
                                  float* __restrict__ C, int M) {
    __shared__ float As[16][16];
    __shared__ float Bs[16][17];
    int tx = threadIdx.x, ty = threadIdx.y;
    int row = blockIdx.y * 16 + ty;
    int col = blockIdx.x * 16 + tx;
    float s = 0.f;
    for (int k0 = 0; k0 < K_DIM; k0 += 16) {
        As[ty][tx] = A[(long)row * K_DIM + k0 + tx];
        Bs[ty][tx] = B[(long)(k0 + ty) * N_DIM + col];
        __syncthreads();
#pragma unroll
        for (int t = 0; t < 16; ++t) s += As[ty][t] * Bs[t][tx];
        __syncthreads();
    }
    C[(long)row * N_DIM + col] = s;
}

// ---------- host launcher ----------
extern "C" void kernel_launch(void* const* d_in, const int* in_sizes, int n_in,
                              void* d_out, int out_size, void* d_ws, size_t ws_size,
                              hipStream_t stream) {
    static const int g_m[N_GROUPS]   = {4096, 2048, 1024, 8192, 512, 3072, 6144, 1024};
    static const int g_off[N_GROUPS] = {0, 4096, 6144, 7168, 15360, 15872, 18944, 25088};

    float* C = (float*)d_out;
    const size_t need = ((size_t)M_TOTAL * K_DIM + (size_t)N_DIM * K_DIM) * 2;

    if (ws_size >= need) {
        unsigned short* Acat = (unsigned short*)d_ws;
        unsigned short* Bt   = Acat + (size_t)M_TOTAL * K_DIM;

        cvt_a_all<<<M_TOTAL / 16, 256, 0, stream>>>(
            (const float*)d_in[0], (const float*)d_in[1], (const float*)d_in[2],
            (const float*)d_in[3], (const float*)d_in[4], (const float*)d_in[5],
            (const float*)d_in[6], (const float*)d_in[7], Acat);
        cvt_bt_kernel<<<dim3(N_DIM / 32, K_DIM / 32), dim3(32, 8), 0, stream>>>(
            (const float*)d_in[8], Bt);

        gemm8_kernel<<<(M_TOTAL / 256) * (N_DIM / 256), 512, 0, stream>>>(Acat, Bt, C);
    } else {
        for (int g = 0; g < N_GROUPS; ++g)
            naive_gemm_kernel<<<dim3(N_DIM / 16, g_m[g] / 16), dim3(16, 16), 0, stream>>>(
                (const float*)d_in[g], (const float*)d_in[8], C + (size_t)g_off[g] * N_DIM,
                g_m[g]);
    }
}